// Round 31
// baseline (36.306 us; speedup 1.0000x reference)
//
#include <hip/hip_runtime.h>
#include <math.h>
#include <stdint.h>

#define NCLS 128
#define NBLK 256
constexpr float ALPHA = 0.5f;
constexpr float BETA_ = 0.5f;
constexpr float EPS_ = 1e-9f;

// ws: gLb[256][128] double | gceb[256] double | gcntb[256][128] uint (atomic-free
// coalesced flush; every slot stored every launch -> no zeroing kernel).

// R30 (rotated pipeline + merge-tree) + ROTATED COLUMN ASSIGNMENT: for row-pair
// u, lane l32 loads chunk (l32-4u)&31 (bijective rotation of the same 1KB; same
// lines, coalescing preserved). Column 0 of row-pair u then lives on its OWNER
// lane l32==4u, so e0 is local to the epilogue: the 8 post-butterfly broadcast
// shuffles vanish (DS/batch 17 -> 9) and the butterfly->epilogue critical path
// loses a dependent DS hop.
__global__ __launch_bounds__(1024, 4) void loss_main(
    const float* __restrict__ y_pred,
    const int*   __restrict__ y_true,
    double* __restrict__ gLb, unsigned int* __restrict__ gcntb,
    double* __restrict__ gceb, int nrows)
{
    __shared__ float    sL[NCLS];
    __shared__ unsigned scnt[NCLS];
    __shared__ float    sce;

    const int t = threadIdx.x;
    if (t == 0) sce = 0.f;
    if (t < NCLS) { sL[t] = 0.f; scnt[t] = 0u; }
    __syncthreads();

    const int lane = t & 63;
    const int half = lane >> 5;
    const int l32  = lane & 31;
    const int wgl  = blockIdx.x * (blockDim.x >> 6) + (t >> 6);   // 0..4095
    const int nW   = gridDim.x * (blockDim.x >> 6);               // 4096
    const int nPairs = nrows >> 1;
    const int step = nW * 8;

    const bool hi16 = (l32 & 16) != 0;
    const bool hi8  = (l32 & 8)  != 0;
    const bool hi4  = (l32 & 4)  != 0;
    const int  uown = (l32 >> 2) & 7;          // row-pair owned by this 4-lane group
    const bool isowner = (l32 & 3) == 0;

    // chunk index this lane loads for row-pair u (rotation): cb[u] = (l32-4u)&31
    int cb[8];
    #pragma unroll
    for (int u = 0; u < 8; ++u) cb[u] = (l32 - (u << 2)) & 31;

    float ce_local = 0.f;

    float4 v[8]; int lab[8];

    auto LOAD = [&](float4 (&V)[8], int (&L)[8], int pb) {
        #pragma unroll
        for (int u = 0; u < 8; ++u) {
            const size_t row = (size_t)((pb + u) << 1) + half;
            V[u] = *reinterpret_cast<const float4*>(y_pred + row * NCLS + (cb[u] << 2));
            L[u] = y_true[((pb + u) << 1) + half];
        }
    };

    int p0 = wgl * 8;
    if (p0 + 7 < nPairs) {
        LOAD(v, lab, p0);
        while (true) {
            // ---- EXP phase: v dies here (S, local e0 on owner lane, tv fold)
            float S[8];
            float e0m = 1.f;
            #pragma unroll
            for (int u = 0; u < 8; ++u) {
                const float ex = __expf(v[u].x), ey = __expf(v[u].y);
                const float ez = __expf(v[u].z), ew = __expf(v[u].w);
                S[u] = (ex + ey) + (ez + ew);
                if (isowner && uown == u) e0m = ex;   // lane 4u holds col 0 of pair u
                // lane holding column lab[u]: (l32-4u)&31 == lab[u]>>2
                if (cb[u] == (lab[u] >> 2)) {
                    const int ls = lab[u] & 3;
                    ce_local += (ls == 0) ? v[u].x : (ls == 1) ? v[u].y
                              : (ls == 2) ? v[u].z : v[u].w;
                }
            }
            // ---- issue NEXT batch's loads now (v dead); labels double-buffered
            const int  pn = p0 + step;
            const bool hn = (pn + 7 < nPairs);
            int labn[8];
            if (hn) LOAD(v, labn, pn);
            __builtin_amdgcn_sched_barrier(0);   // loads may not sink below here

            // ---- merge-tree reduce: 9 shuffles for all 8 row-pairs per half
            float A0, A1, A2, A3;
            {
                const float s0 = hi16 ? S[0] : S[4];
                const float s1 = hi16 ? S[1] : S[5];
                const float s2 = hi16 ? S[2] : S[6];
                const float s3 = hi16 ? S[3] : S[7];
                A0 = (hi16 ? S[4] : S[0]) + __shfl_xor(s0, 16);
                A1 = (hi16 ? S[5] : S[1]) + __shfl_xor(s1, 16);
                A2 = (hi16 ? S[6] : S[2]) + __shfl_xor(s2, 16);
                A3 = (hi16 ? S[7] : S[3]) + __shfl_xor(s3, 16);
            }
            float B0, B1;
            {
                const float s0 = hi8 ? A0 : A2;
                const float s1 = hi8 ? A1 : A3;
                B0 = (hi8 ? A2 : A0) + __shfl_xor(s0, 8);
                B1 = (hi8 ? A3 : A1) + __shfl_xor(s1, 8);
            }
            float C0;
            {
                const float s = hi4 ? B0 : B1;
                C0 = (hi4 ? B1 : B0) + __shfl_xor(s, 4);
            }
            C0 += __shfl_xor(C0, 2);
            C0 += __shfl_xor(C0, 1);             // C0 = S_total for row-pair uown

            int labm = 0;
            #pragma unroll
            for (int u = 0; u < 8; ++u) if (uown == u) labm = lab[u];

            // ---- wave-parallel epilogue: 16 owner lanes (8 per half); e0m local
            if (isowner) {
                const float Sm = C0;
                const float logS = __logf(Sm);
                ce_local -= logS;
                const float d = (labm == 0) ? e0m : (Sm - e0m);
                const float c0 = __logf(__fmaf_rn(EPS_, Sm, d)) - logS;
                const float contrib = (labm == 0) ? ALPHA * c0 : c0;
                atomicAdd(&sL[labm], contrib);
                atomicAdd(&scnt[labm], 1u);
            }
            p0 = pn;
            if (!hn) break;
            #pragma unroll
            for (int u = 0; u < 8; ++u) lab[u] = labn[u];
        }
    }
    // tail: leftover single pairs (empty at 262144 rows; kept for generality)
    for (; p0 < nPairs; ++p0) {
        const int row = (p0 << 1) + half;
        const float4 vv = *reinterpret_cast<const float4*>(
            y_pred + (size_t)row * NCLS + (l32 << 2));
        const int lb2 = y_true[row];
        const float ex = __expf(vv.x), ey = __expf(vv.y);
        const float ez = __expf(vv.z), ew = __expf(vv.w);
        float S = (ex + ey) + (ez + ew);
        if ((lb2 >> 2) == l32) {
            const int ls = lb2 & 3;
            ce_local += (ls == 0) ? vv.x : (ls == 1) ? vv.y : (ls == 2) ? vv.z : vv.w;
        }
        #pragma unroll
        for (int off = 16; off; off >>= 1) S += __shfl_xor(S, off);
        if (l32 == 0) {
            const float logS = __logf(S);
            ce_local -= logS;
            const float d = (lb2 == 0) ? ex : (S - ex);
            const float c0 = __logf(__fmaf_rn(EPS_, S, d)) - logS;
            const float contrib = (lb2 == 0) ? ALPHA * c0 : c0;
            atomicAdd(&sL[lb2], contrib);
            atomicAdd(&scnt[lb2], 1u);
        }
    }
    if ((nrows & 1) && wgl == 0) {
        const int row = nrows - 1;
        const float4 vv = *reinterpret_cast<const float4*>(
            y_pred + (size_t)row * NCLS + (l32 << 2));
        const int lb2 = y_true[row];
        if (half == 0) {
            const float ex = __expf(vv.x), ey = __expf(vv.y);
            const float ez = __expf(vv.z), ew = __expf(vv.w);
            float S = (ex + ey) + (ez + ew);
            if ((lb2 >> 2) == l32) {
                const int ls = lb2 & 3;
                ce_local += (ls == 0) ? vv.x : (ls == 1) ? vv.y : (ls == 2) ? vv.z : vv.w;
            }
            #pragma unroll
            for (int off = 16; off; off >>= 1) S += __shfl_xor(S, off);
            if (l32 == 0) {
                const float logS = __logf(S);
                ce_local -= logS;
                const float d = (lb2 == 0) ? ex : (S - ex);
                const float c0 = __logf(__fmaf_rn(EPS_, S, d)) - logS;
                const float contrib = (lb2 == 0) ? ALPHA * c0 : c0;
                atomicAdd(&sL[lb2], contrib);
                atomicAdd(&scnt[lb2], 1u);
            }
        }
    }

    float lp = ce_local;
    #pragma unroll
    for (int off = 32; off; off >>= 1) lp += __shfl_xor(lp, off);
    if (lane == 0) atomicAdd(&sce, lp);
    __syncthreads();

    // coalesced write-flush: block owns row blockIdx.x of [blk][cls] arrays.
    if (t < NCLS) {
        gLb[(size_t)blockIdx.x * NCLS + t]   = (double)sL[t];
        gcntb[(size_t)blockIdx.x * NCLS + t] = scnt[t];
    }
    if (t == 0) gceb[blockIdx.x] = (double)sce;
}

// Parallel finalize: 1024 threads. 8 threads per class x 32 slots, coalesced
// (for fixed slot b, lanes read consecutive classes). LDS tree + wave butterflies.
__global__ __launch_bounds__(1024) void loss_final(
    const double* __restrict__ gLb,          // [256][128]
    const unsigned int* __restrict__ gcntb,  // [256][128]
    const double* __restrict__ gceb,         // [256]
    float* __restrict__ out, int nrows)
{
    __shared__ double sLc[8][NCLS];
    __shared__ double snc[8][NCLS];
    __shared__ double sred[4];

    const int t = threadIdx.x;
    const int c = t & (NCLS - 1);
    const int g = t >> 7;                    // 0..7

    double Lc = 0.0, nc = 0.0;
    for (int b = g * 32; b < g * 32 + 32; ++b) {
        Lc += gLb[(size_t)b * NCLS + c];
        nc += (double)gcntb[(size_t)b * NCLS + c];
    }
    sLc[g][c] = Lc; snc[g][c] = nc;
    __syncthreads();

    if (t < NCLS) {
        double L = 0.0, n = 0.0;
        #pragma unroll
        for (int gg = 0; gg < 8; ++gg) { L += sLc[gg][t]; n += snc[gg][t]; }
        sLc[0][t] = L; snc[0][t] = n;
    }
    __syncthreads();

    const double denom = (double)nrows - snc[0][0];
    double local = 0.0;
    if (t < NCLS) {
        const double L = sLc[0][t], n = snc[0][t];
        local = (t == 0) ? L : (double)BETA_ * (1.0 - n / denom) * L;
    }
    #pragma unroll
    for (int off = 32; off; off >>= 1) local += __shfl_xor(local, off);
    if (t < NCLS && (t & 63) == 0) sred[t >> 6] = local;   // sred[0], sred[1]

    if (t >= 128 && t < 192) {               // one wave sums gceb[256]
        const int l = t - 128;
        double cep = gceb[l] + gceb[l + 64] + gceb[l + 128] + gceb[l + 192];
        #pragma unroll
        for (int off = 32; off; off >>= 1) cep += __shfl_xor(cep, off);
        if (l == 0) sred[2] = cep;
    }
    __syncthreads();

    if (t == 0) {
        const double ce = -sred[2] / (double)nrows;
        out[0] = (float)(ce - (sred[0] + sred[1]) / (double)nrows);
    }
}

extern "C" void kernel_launch(void* const* d_in, const int* in_sizes, int n_in,
                              void* d_out, int out_size, void* d_ws, size_t ws_size,
                              hipStream_t stream) {
    const float* y_pred = (const float*)d_in[0];
    const int*   y_true = (const int*)d_in[1];
    const int nrows = in_sizes[1];

    double*   gLb   = (double*)d_ws;                          // 262144 B
    double*   gceb  = (double*)((char*)d_ws + 262144);        // 2048 B
    unsigned* gcntb = (unsigned*)((char*)d_ws + 264192);      // 131072 B

    loss_main<<<dim3(NBLK), dim3(1024), 0, stream>>>(y_pred, y_true, gLb, gcntb, gceb, nrows);
    loss_final<<<dim3(1), dim3(1024), 0, stream>>>(gLb, gcntb, gceb, (float*)d_out, nrows);
}

// Round 32
// 35.852 us; speedup vs baseline: 1.0127x; 1.0127x over previous
//
#include <hip/hip_runtime.h>
#include <math.h>
#include <stdint.h>

#define NCLS 128
#define NBLK 256
constexpr float ALPHA = 0.5f;
constexpr float BETA_ = 0.5f;
constexpr float EPS_ = 1e-9f;

// ws: gLb[256][128] double | gceb[256] double | gcntb[256][128] uint (atomic-free
// coalesced flush; every slot stored every launch -> no zeroing kernel).

// R30 CHAMPION (revert of R31's rotated-column regression): rotated software
// pipeline (next batch's loads issued where v[] dies, sched_barrier-pinned) +
// merge-tree reduction (9 shuffles for 16 rows vs 40) + wave-parallel epilogue
// + atomic-free coalesced write-flush + parallel finalize. 35.7 us measured.
__global__ __launch_bounds__(1024, 4) void loss_main(
    const float* __restrict__ y_pred,
    const int*   __restrict__ y_true,
    double* __restrict__ gLb, unsigned int* __restrict__ gcntb,
    double* __restrict__ gceb, int nrows)
{
    __shared__ float    sL[NCLS];
    __shared__ unsigned scnt[NCLS];
    __shared__ float    sce;

    const int t = threadIdx.x;
    if (t == 0) sce = 0.f;
    if (t < NCLS) { sL[t] = 0.f; scnt[t] = 0u; }
    __syncthreads();

    const int lane = t & 63;
    const int half = lane >> 5;
    const int l32  = lane & 31;
    const int wgl  = blockIdx.x * (blockDim.x >> 6) + (t >> 6);   // 0..4095
    const int nW   = gridDim.x * (blockDim.x >> 6);               // 4096
    const int nPairs = nrows >> 1;
    const int step = nW * 8;

    const bool hi16 = (l32 & 16) != 0;
    const bool hi8  = (l32 & 8)  != 0;
    const bool hi4  = (l32 & 4)  != 0;
    const int  uown = (l32 >> 2) & 7;          // row-pair owned by this 4-lane group
    const bool isowner = (l32 & 3) == 0;

    float ce_local = 0.f;

    float4 v[8]; int lab[8];

    auto LOAD = [&](float4 (&V)[8], int (&L)[8], int pb) {
        const float* base = y_pred + ((size_t)(pb << 1) + half) * NCLS + (l32 << 2);
        #pragma unroll
        for (int u = 0; u < 8; ++u) {
            V[u] = *reinterpret_cast<const float4*>(base + (size_t)(u << 1) * NCLS);
            L[u] = y_true[((pb + u) << 1) + half];
        }
    };

    int p0 = wgl * 8;
    if (p0 + 7 < nPairs) {
        LOAD(v, lab, p0);
        while (true) {
            // ---- EXP phase: v dies here (S, e0, owner-lane tv fold)
            float S[8], e0[8];
            #pragma unroll
            for (int u = 0; u < 8; ++u) {
                const float ex = __expf(v[u].x), ey = __expf(v[u].y);
                const float ez = __expf(v[u].z), ew = __expf(v[u].w);
                e0[u] = ex;                      // valid on lane 0/32 (col 0) only
                S[u]  = (ex + ey) + (ez + ew);
                if ((lab[u] >> 2) == l32) {      // owner lane folds target logit
                    const int ls = lab[u] & 3;
                    ce_local += (ls == 0) ? v[u].x : (ls == 1) ? v[u].y
                              : (ls == 2) ? v[u].z : v[u].w;
                }
            }
            // ---- issue NEXT batch's loads now (v dead); labels double-buffered
            const int  pn = p0 + step;
            const bool hn = (pn + 7 < nPairs);
            int labn[8];
            if (hn) LOAD(v, labn, pn);
            __builtin_amdgcn_sched_barrier(0);   // loads may not sink below here

            // ---- merge-tree reduce: 9 shuffles total for all 8 row-pairs/half
            float A0, A1, A2, A3;
            {
                const float s0 = hi16 ? S[0] : S[4];
                const float s1 = hi16 ? S[1] : S[5];
                const float s2 = hi16 ? S[2] : S[6];
                const float s3 = hi16 ? S[3] : S[7];
                A0 = (hi16 ? S[4] : S[0]) + __shfl_xor(s0, 16);
                A1 = (hi16 ? S[5] : S[1]) + __shfl_xor(s1, 16);
                A2 = (hi16 ? S[6] : S[2]) + __shfl_xor(s2, 16);
                A3 = (hi16 ? S[7] : S[3]) + __shfl_xor(s3, 16);
            }
            float B0, B1;
            {
                const float s0 = hi8 ? A0 : A2;
                const float s1 = hi8 ? A1 : A3;
                B0 = (hi8 ? A2 : A0) + __shfl_xor(s0, 8);
                B1 = (hi8 ? A3 : A1) + __shfl_xor(s1, 8);
            }
            float C0;
            {
                const float s = hi4 ? B0 : B1;
                C0 = (hi4 ? B1 : B0) + __shfl_xor(s, 4);
            }
            C0 += __shfl_xor(C0, 2);
            C0 += __shfl_xor(C0, 1);             // C0 = S_total for row-pair uown

            // ---- e0 broadcast to owner groups (8 shuffles, select-style)
            float e0m = 1.f;
            #pragma unroll
            for (int u = 0; u < 8; ++u) {
                const float b = __shfl(e0[u], half << 5);
                if (uown == u) e0m = b;
            }
            int labm = 0;
            #pragma unroll
            for (int u = 0; u < 8; ++u) if (uown == u) labm = lab[u];

            // ---- wave-parallel epilogue: 16 owner lanes (8 per half)
            if (isowner) {
                const float Sm = C0;
                const float logS = __logf(Sm);
                ce_local -= logS;
                const float d = (labm == 0) ? e0m : (Sm - e0m);
                const float c0 = __logf(__fmaf_rn(EPS_, Sm, d)) - logS;
                const float contrib = (labm == 0) ? ALPHA * c0 : c0;
                atomicAdd(&sL[labm], contrib);
                atomicAdd(&scnt[labm], 1u);
            }
            p0 = pn;
            if (!hn) break;
            #pragma unroll
            for (int u = 0; u < 8; ++u) lab[u] = labn[u];
        }
    }
    // tail: leftover single pairs (empty at 262144 rows; kept for generality)
    for (; p0 < nPairs; ++p0) {
        const int row = (p0 << 1) + half;
        const float4 vv = *reinterpret_cast<const float4*>(
            y_pred + (size_t)row * NCLS + (l32 << 2));
        const int lb2 = y_true[row];
        const float ex = __expf(vv.x), ey = __expf(vv.y);
        const float ez = __expf(vv.z), ew = __expf(vv.w);
        float S = (ex + ey) + (ez + ew);
        if ((lb2 >> 2) == l32) {
            const int ls = lb2 & 3;
            ce_local += (ls == 0) ? vv.x : (ls == 1) ? vv.y : (ls == 2) ? vv.z : vv.w;
        }
        #pragma unroll
        for (int off = 16; off; off >>= 1) S += __shfl_xor(S, off);
        if (l32 == 0) {
            const float logS = __logf(S);
            ce_local -= logS;
            const float d = (lb2 == 0) ? ex : (S - ex);
            const float c0 = __logf(__fmaf_rn(EPS_, S, d)) - logS;
            const float contrib = (lb2 == 0) ? ALPHA * c0 : c0;
            atomicAdd(&sL[lb2], contrib);
            atomicAdd(&scnt[lb2], 1u);
        }
    }
    if ((nrows & 1) && wgl == 0) {
        const int row = nrows - 1;
        const float4 vv = *reinterpret_cast<const float4*>(
            y_pred + (size_t)row * NCLS + (l32 << 2));
        const int lb2 = y_true[row];
        if (half == 0) {
            const float ex = __expf(vv.x), ey = __expf(vv.y);
            const float ez = __expf(vv.z), ew = __expf(vv.w);
            float S = (ex + ey) + (ez + ew);
            if ((lb2 >> 2) == l32) {
                const int ls = lb2 & 3;
                ce_local += (ls == 0) ? vv.x : (ls == 1) ? vv.y : (ls == 2) ? vv.z : vv.w;
            }
            #pragma unroll
            for (int off = 16; off; off >>= 1) S += __shfl_xor(S, off);
            if (l32 == 0) {
                const float logS = __logf(S);
                ce_local -= logS;
                const float d = (lb2 == 0) ? ex : (S - ex);
                const float c0 = __logf(__fmaf_rn(EPS_, S, d)) - logS;
                const float contrib = (lb2 == 0) ? ALPHA * c0 : c0;
                atomicAdd(&sL[lb2], contrib);
                atomicAdd(&scnt[lb2], 1u);
            }
        }
    }

    float lp = ce_local;
    #pragma unroll
    for (int off = 32; off; off >>= 1) lp += __shfl_xor(lp, off);
    if (lane == 0) atomicAdd(&sce, lp);
    __syncthreads();

    // coalesced write-flush: block owns row blockIdx.x of [blk][cls] arrays.
    if (t < NCLS) {
        gLb[(size_t)blockIdx.x * NCLS + t]   = (double)sL[t];
        gcntb[(size_t)blockIdx.x * NCLS + t] = scnt[t];
    }
    if (t == 0) gceb[blockIdx.x] = (double)sce;
}

// Parallel finalize: 1024 threads. 8 threads per class x 32 slots, coalesced
// (for fixed slot b, lanes read consecutive classes). LDS tree + wave butterflies.
__global__ __launch_bounds__(1024) void loss_final(
    const double* __restrict__ gLb,          // [256][128]
    const unsigned int* __restrict__ gcntb,  // [256][128]
    const double* __restrict__ gceb,         // [256]
    float* __restrict__ out, int nrows)
{
    __shared__ double sLc[8][NCLS];
    __shared__ double snc[8][NCLS];
    __shared__ double sred[4];

    const int t = threadIdx.x;
    const int c = t & (NCLS - 1);
    const int g = t >> 7;                    // 0..7

    double Lc = 0.0, nc = 0.0;
    for (int b = g * 32; b < g * 32 + 32; ++b) {
        Lc += gLb[(size_t)b * NCLS + c];
        nc += (double)gcntb[(size_t)b * NCLS + c];
    }
    sLc[g][c] = Lc; snc[g][c] = nc;
    __syncthreads();

    if (t < NCLS) {
        double L = 0.0, n = 0.0;
        #pragma unroll
        for (int gg = 0; gg < 8; ++gg) { L += sLc[gg][t]; n += snc[gg][t]; }
        sLc[0][t] = L; snc[0][t] = n;
    }
    __syncthreads();

    const double denom = (double)nrows - snc[0][0];
    double local = 0.0;
    if (t < NCLS) {
        const double L = sLc[0][t], n = snc[0][t];
        local = (t == 0) ? L : (double)BETA_ * (1.0 - n / denom) * L;
    }
    #pragma unroll
    for (int off = 32; off; off >>= 1) local += __shfl_xor(local, off);
    if (t < NCLS && (t & 63) == 0) sred[t >> 6] = local;   // sred[0], sred[1]

    if (t >= 128 && t < 192) {               // one wave sums gceb[256]
        const int l = t - 128;
        double cep = gceb[l] + gceb[l + 64] + gceb[l + 128] + gceb[l + 192];
        #pragma unroll
        for (int off = 32; off; off >>= 1) cep += __shfl_xor(cep, off);
        if (l == 0) sred[2] = cep;
    }
    __syncthreads();

    if (t == 0) {
        const double ce = -sred[2] / (double)nrows;
        out[0] = (float)(ce - (sred[0] + sred[1]) / (double)nrows);
    }
}

extern "C" void kernel_launch(void* const* d_in, const int* in_sizes, int n_in,
                              void* d_out, int out_size, void* d_ws, size_t ws_size,
                              hipStream_t stream) {
    const float* y_pred = (const float*)d_in[0];
    const int*   y_true = (const int*)d_in[1];
    const int nrows = in_sizes[1];

    double*   gLb   = (double*)d_ws;                          // 262144 B
    double*   gceb  = (double*)((char*)d_ws + 262144);        // 2048 B
    unsigned* gcntb = (unsigned*)((char*)d_ws + 264192);      // 131072 B

    loss_main<<<dim3(NBLK), dim3(1024), 0, stream>>>(y_pred, y_true, gLb, gcntb, gceb, nrows);
    loss_final<<<dim3(1), dim3(1024), 0, stream>>>(gLb, gcntb, gceb, (float*)d_out, nrows);
}